// Round 6
// baseline (32.205 us; speedup 1.0000x reference)
//
#include <hip/hip_runtime.h>

// SpectralLoss: mean over all 8x8 blocks of (T (x-y) T^T)^2 * W
// One thread per 8x8 block; even/odd DCT butterflies cut VALU ~32%
// (T[i][7-j] = +/-T[i][j] exactly for the orthonormal DCT-II matrix).
// Single kernel + per-WG atomicAdd (order-nondeterminism ~1e-5 << 1.56e-3
// threshold); 4-byte memset node zeroes out[] each replay.

#define WG 256
#define NWG 768
#define INV_N (1.0f/12582912.0f)   // 16*3*512*512

typedef float v4f __attribute__((ext_vector_type(4)));

__global__ __launch_bounds__(WG) void spectral_fused(
    const float* __restrict__ x,
    const float* __restrict__ y,
    const float* __restrict__ Tm,
    const float* __restrict__ Wm,
    float* __restrict__ out)
{
    const int tid = threadIdx.x;
    const int p   = blockIdx.x * WG + tid;   // 8x8-block id
    const int img = p >> 12;                 // 4096 blocks per image plane
    const int rem = p & 4095;
    const int base = img * 262144 + (rem >> 6) * 4096 + (rem & 63) * 8;

    // Half-rows of T: TE[k][j]=T[2k][j], TO[k][j]=T[2k+1][j], j=0..3.
    // Uniform addresses -> scalar loads (SGPRs).
    float TE[4][4], TO[4][4];
#pragma unroll
    for (int k = 0; k < 4; ++k) {
        float4 e = *reinterpret_cast<const float4*>(Tm + 16*k);
        float4 o = *reinterpret_cast<const float4*>(Tm + 16*k + 8);
        TE[k][0]=e.x; TE[k][1]=e.y; TE[k][2]=e.z; TE[k][3]=e.w;
        TO[k][0]=o.x; TO[k][1]=o.y; TO[k][2]=o.z; TO[k][3]=o.w;
    }

    // Phase 1: M[r][l] = sum_j D[r][j]*T[l][j] via even/odd split.
    float M[8][8];
#pragma unroll
    for (int r = 0; r < 8; ++r) {
        const v4f* xp = reinterpret_cast<const v4f*>(x + base + r*512);
        const v4f* yp = reinterpret_cast<const v4f*>(y + base + r*512);
        v4f a0 = __builtin_nontemporal_load(xp);
        v4f a1 = __builtin_nontemporal_load(xp + 1);
        v4f b0 = __builtin_nontemporal_load(yp);
        v4f b1 = __builtin_nontemporal_load(yp + 1);
        float v0=a0.x-b0.x, v1=a0.y-b0.y, v2=a0.z-b0.z, v3=a0.w-b0.w;
        float v4=a1.x-b1.x, v5=a1.y-b1.y, v6=a1.z-b1.z, v7=a1.w-b1.w;
        float e0=v0+v7, e1=v1+v6, e2=v2+v5, e3=v3+v4;
        float o0=v0-v7, o1=v1-v6, o2=v2-v5, o3=v3-v4;
#pragma unroll
        for (int k = 0; k < 4; ++k) {
            M[r][2*k]   = e0*TE[k][0] + e1*TE[k][1] + e2*TE[k][2] + e3*TE[k][3];
            M[r][2*k+1] = o0*TO[k][0] + o1*TO[k][1] + o2*TO[k][2] + o3*TO[k][3];
        }
    }

    // Phase 2: column butterflies in place.
    // M[r][l] <- M[r][l]+M[7-r][l] (even part), M[7-r][l] <- diff (odd part).
#pragma unroll
    for (int l = 0; l < 8; ++l) {
#pragma unroll
        for (int r = 0; r < 4; ++r) {
            float a = M[r][l], b = M[7-r][l];
            M[r][l]   = a + b;
            M[7-r][l] = a - b;
        }
    }

    // d[2k][l]   = sum_{r=0..3} TE[k][r]*M[r][l]
    // d[2k+1][l] = sum_{r=0..3} TO[k][r]*M[7-r][l]
    float s = 0.0f;
#pragma unroll
    for (int k = 0; k < 4; ++k) {
        float4 w0 = reinterpret_cast<const float4*>(Wm)[4*k];     // W[2k][0..3]
        float4 w1 = reinterpret_cast<const float4*>(Wm)[4*k+1];   // W[2k][4..7]
        float4 w2 = reinterpret_cast<const float4*>(Wm)[4*k+2];   // W[2k+1][0..3]
        float4 w3 = reinterpret_cast<const float4*>(Wm)[4*k+3];   // W[2k+1][4..7]
        float we[8] = {w0.x,w0.y,w0.z,w0.w,w1.x,w1.y,w1.z,w1.w};
        float wo[8] = {w2.x,w2.y,w2.z,w2.w,w3.x,w3.y,w3.z,w3.w};
#pragma unroll
        for (int l = 0; l < 8; ++l) {
            float de = TE[k][0]*M[0][l] + TE[k][1]*M[1][l]
                     + TE[k][2]*M[2][l] + TE[k][3]*M[3][l];
            float dodd = TO[k][0]*M[7][l] + TO[k][1]*M[6][l]
                       + TO[k][2]*M[5][l] + TO[k][3]*M[4][l];
            s += we[l]*de*de;
            s += wo[l]*dodd*dodd;
        }
    }

    // Deterministic WG reduction, then one atomic per WG.
#pragma unroll
    for (int off = 32; off > 0; off >>= 1) s += __shfl_down(s, off, 64);
    __shared__ float wsum[WG/64];
    if ((tid & 63) == 0) wsum[tid >> 6] = s;
    __syncthreads();
    if (tid == 0)
        atomicAdd(out, (wsum[0]+wsum[1]+wsum[2]+wsum[3]) * INV_N);
}

extern "C" void kernel_launch(void* const* d_in, const int* in_sizes, int n_in,
                              void* d_out, int out_size, void* d_ws, size_t ws_size,
                              hipStream_t stream) {
    const float* x  = (const float*)d_in[0];   // input  (16,3,512,512) f32
    const float* y  = (const float*)d_in[1];   // target (16,3,512,512) f32
    const float* Tm = (const float*)d_in[2];   // 8x8 DCT
    const float* Wm = (const float*)d_in[3];   // 8x8 weight
    float* out = (float*)d_out;                // scalar f32

    hipMemsetAsync(out, 0, sizeof(float), stream);  // zero accumulator each call
    spectral_fused<<<NWG, WG, 0, stream>>>(x, y, Tm, Wm, out);
}